// Round 1
// baseline (39.448 us; speedup 1.0000x reference)
//
#include <hip/hip_runtime.h>
#include <stdint.h>

// Problem constants (from reference setup_inputs)
#define BB   32      // batch
#define SS   2048    // sequence length
#define NCH  30      // char alphabet
#define PP   13      // pattern length
#define NN   512     // number of patterns
#define WW   32      // SS / 64 bit-words per row

// ---------------------------------------------------------------------------
// Kernel 1: discretize patterns.
// patterns layout [c=30][p=13][1][n=512], col = p*512+n.
// Output per column: argmax char, or 255 = wildcard (col sum <= 0 -> discrete
// all-zero, no constraint), or 254 = dead (tied max -> pattern_sums gains >=2
// from this column but conv can contribute at most 1 -> pattern never matches).
// ---------------------------------------------------------------------------
__global__ void k_discretize(const float* __restrict__ patterns,
                             uint8_t* __restrict__ pat_chars) {
    int col = blockIdx.x * blockDim.x + threadIdx.x;  // p*NN + n
    if (col >= PP * NN) return;
    float mx = -1e30f;
    float sum = 0.f;
    int arg = 0;
    for (int c = 0; c < NCH; ++c) {
        float v = patterns[(size_t)c * (PP * NN) + col];
        sum += v;
        if (v > mx) { mx = v; arg = c; }
    }
    int cnt = 0;
    for (int c = 0; c < NCH; ++c) {
        float v = patterns[(size_t)c * (PP * NN) + col];
        cnt += (v == mx) ? 1 : 0;
    }
    uint8_t o;
    if (!(sum > 0.f))  o = 255;       // wildcard column
    else if (cnt > 1)  o = 254;       // dead pattern marker
    else               o = (uint8_t)arg;
    pat_chars[col] = o;
}

// ---------------------------------------------------------------------------
// Kernel 2: per-(b,c) occurrence bitmaps from the one-hot input.
// input_ layout [b][c][s]; bit j of bits[(b*30+c)*32 + w] = (input one-hot at
// s = w*64+j). One wave per 64-bit word via __ballot (wave = 64 lanes).
// ---------------------------------------------------------------------------
__global__ void k_bits(const float* __restrict__ input_,
                       uint64_t* __restrict__ bits) {
    int gid  = blockIdx.x * blockDim.x + threadIdx.x;
    int word = gid >> 6;          // (b*NCH + c)*WW + w
    int lane = gid & 63;
    if (word >= BB * NCH * WW) return;
    int bc = word >> 5;           // b*NCH + c
    int w  = word & (WW - 1);
    float v = input_[(size_t)bc * SS + (size_t)w * 64 + lane];
    uint64_t m = __ballot(v > 0.5f);
    if (lane == 0) bits[word] = m;
}

// ---------------------------------------------------------------------------
// Kernel 3: bit-parallel match + expand to fp32.
// Block = 256 threads handles one b and 8 consecutive n.
// Phase A: thread t -> (n_local = t>>5, w = t&31): 64 match bits via 13
//          shifted ANDs of the char bitmaps.  Tail s >= 2036 cleared (pad
//          region of conv) unless the pattern has zero constraints.
// Phase B: LDS-staged expansion, perfectly coalesced float4 stores.
// ---------------------------------------------------------------------------
__global__ void k_match(const uint8_t* __restrict__ pat_chars,
                        const uint64_t* __restrict__ bits,
                        float* __restrict__ out) {
    __shared__ uint64_t masks[8][WW];
    const int b  = blockIdx.x >> 6;    // 64 n-groups of 8 per batch
    const int ng = blockIdx.x & 63;
    const int t  = threadIdx.x;
    const int nl = t >> 5;
    const int w  = t & (WW - 1);
    const int n  = ng * 8 + nl;

    const uint64_t* bb = bits + (size_t)b * NCH * WW;

    uint64_t m = ~0ULL;
    bool has_any = false;   // sums > 0 ?
    bool dead    = false;
#pragma unroll
    for (int p = 0; p < PP; ++p) {
        int c = pat_chars[p * NN + n];
        if (c == 255) continue;        // wildcard column
        has_any = true;
        if (c == 254) { dead = true; continue; }
        uint64_t lo = bb[c * WW + w];
        uint64_t hi = (w < WW - 1) ? bb[c * WW + w + 1] : 0ULL;
        uint64_t word = (p == 0) ? lo : ((lo >> p) | (hi << (64 - p)));
        m &= word;
    }
    if (dead) m = 0ULL;
    // pad region: s in [2036,2048) must be 0 when pattern_sums > 0
    if (w == WW - 1 && has_any) m &= ((1ULL << 52) - 1);

    masks[nl][w] = m;
    __syncthreads();

    // Phase B: write 8 rows x 2048 floats, coalesced float4
    size_t base = ((size_t)b * NN + (size_t)ng * 8) * SS;
#pragma unroll
    for (int r = 0; r < 8; ++r) {
        float4* rowp = (float4*)(out + base + (size_t)r * SS);
#pragma unroll
        for (int j = 0; j < 2; ++j) {
            int i4 = t + j * 256;              // float4 index within row [0,512)
            uint64_t mm = masks[r][i4 >> 4];
            int sh = (i4 & 15) * 4;
            float4 v;
            v.x = ((mm >> (sh + 0)) & 1ULL) ? 1.f : 0.f;
            v.y = ((mm >> (sh + 1)) & 1ULL) ? 1.f : 0.f;
            v.z = ((mm >> (sh + 2)) & 1ULL) ? 1.f : 0.f;
            v.w = ((mm >> (sh + 3)) & 1ULL) ? 1.f : 0.f;
            rowp[i4] = v;
        }
    }
}

// ---------------------------------------------------------------------------
extern "C" void kernel_launch(void* const* d_in, const int* in_sizes, int n_in,
                              void* d_out, int out_size, void* d_ws, size_t ws_size,
                              hipStream_t stream) {
    const float* input_   = (const float*)d_in[0];   // [32,30,2048,1]
    const float* patterns = (const float*)d_in[1];   // [30,13,1,512]
    float* out = (float*)d_out;                      // [32,512,2048,1]

    uint8_t*  pat_chars = (uint8_t*)d_ws;                          // 6656 B
    uint64_t* bits      = (uint64_t*)((char*)d_ws + 8192);         // 245760 B

    // K1: 13*512 = 6656 columns
    k_discretize<<<(PP * NN + 255) / 256, 256, 0, stream>>>(patterns, pat_chars);
    // K2: 32*30*32 words, one wave each -> 30720*64/256 blocks
    k_bits<<<(BB * NCH * WW * 64) / 256, 256, 0, stream>>>(input_, bits);
    // K3: one block per (b, group-of-8 n) -> 32*64 = 2048 blocks
    k_match<<<BB * (NN / 8), 256, 0, stream>>>(pat_chars, bits, out);
}